// Round 1
// baseline (125.121 us; speedup 1.0000x reference)
//
#include <hip/hip_runtime.h>
#include <hip/hip_bf16.h>

// out[b,o,h,w] = clip( sum_c x[b,c,h,w] * w2d[o,c] * styles[b,c] + bias[o], -256, 256 )
// styles[b,c] = (dot(w[b,:], affine_w[c,:]) / sqrt(512) + affine_b[c]) / sqrt(256)
// B=8, C_in=256, H=W=256, C_out=3, w_dim=512.  All fp32.

#define B_    8
#define CIN   256
#define HW    65536          // 256*256
#define HW4   16384          // HW/4
#define COUT  3
#define WDIM  512

__global__ __launch_bounds__(256) void styles_kernel(
    const float* __restrict__ w,          // (B, 512)
    const float* __restrict__ affine_w,   // (256, 512)
    const float* __restrict__ affine_b,   // (256,)
    float* __restrict__ styles)           // (B, 256) out
{
    const int b = blockIdx.x;
    const int c = threadIdx.x;            // 0..255
    __shared__ float ws[WDIM];
    for (int i = threadIdx.x; i < WDIM; i += 256) ws[i] = w[b * WDIM + i];
    __syncthreads();

    const float4* aw = (const float4*)(affine_w + (size_t)c * WDIM);
    const float4* wv = (const float4*)ws;
    float acc = 0.f;
#pragma unroll 8
    for (int i = 0; i < WDIM / 4; ++i) {
        float4 a = aw[i];
        float4 q = wv[i];
        acc += a.x * q.x + a.y * q.y + a.z * q.z + a.w * q.w;
    }
    const float rs512 = 0.044194173824159216f;  // 1/sqrt(512)
    const float rs256 = 0.0625f;                // 1/sqrt(256)
    styles[b * CIN + c] = (acc * rs512 + affine_b[c]) * rs256;
}

__global__ __launch_bounds__(256) void modconv_kernel(
    const float* __restrict__ x,        // (B, 256, 256, 256)
    const float* __restrict__ styles,   // (B, 256)
    const float* __restrict__ weight,   // (3, 256, 1, 1) -> (3,256)
    const float* __restrict__ bias,     // (3,)
    float* __restrict__ out)            // (B, 3, 256, 256)
{
    const int b    = blockIdx.y;
    const int tile = blockIdx.x;        // 64 tiles of 1024 floats each
    const int tid  = threadIdx.x;       // 256

    __shared__ float m0s[CIN];
    __shared__ float m1s[CIN];
    __shared__ float m2s[CIN];
    {
        float s = styles[b * CIN + tid];
        m0s[tid] = weight[0 * CIN + tid] * s;
        m1s[tid] = weight[1 * CIN + tid] * s;
        m2s[tid] = weight[2 * CIN + tid] * s;
    }
    __syncthreads();

    // per-thread float4 position within the (b) image
    const float4* xp = (const float4*)x + (size_t)b * CIN * HW4 + (size_t)tile * 256 + tid;

    const float b0 = bias[0], b1 = bias[1], b2 = bias[2];
    float4 a0 = {b0, b0, b0, b0};
    float4 a1 = {b1, b1, b1, b1};
    float4 a2 = {b2, b2, b2, b2};

#pragma unroll 8
    for (int c = 0; c < CIN; ++c) {
        float4 xv = xp[(size_t)c * HW4];
        float w0 = m0s[c], w1 = m1s[c], w2 = m2s[c];
        a0.x = fmaf(xv.x, w0, a0.x);
        a0.y = fmaf(xv.y, w0, a0.y);
        a0.z = fmaf(xv.z, w0, a0.z);
        a0.w = fmaf(xv.w, w0, a0.w);
        a1.x = fmaf(xv.x, w1, a1.x);
        a1.y = fmaf(xv.y, w1, a1.y);
        a1.z = fmaf(xv.z, w1, a1.z);
        a1.w = fmaf(xv.w, w1, a1.w);
        a2.x = fmaf(xv.x, w2, a2.x);
        a2.y = fmaf(xv.y, w2, a2.y);
        a2.z = fmaf(xv.z, w2, a2.z);
        a2.w = fmaf(xv.w, w2, a2.w);
    }

    const float CL = 256.0f;
    a0.x = fminf(fmaxf(a0.x, -CL), CL);
    a0.y = fminf(fmaxf(a0.y, -CL), CL);
    a0.z = fminf(fmaxf(a0.z, -CL), CL);
    a0.w = fminf(fmaxf(a0.w, -CL), CL);
    a1.x = fminf(fmaxf(a1.x, -CL), CL);
    a1.y = fminf(fmaxf(a1.y, -CL), CL);
    a1.z = fminf(fmaxf(a1.z, -CL), CL);
    a1.w = fminf(fmaxf(a1.w, -CL), CL);
    a2.x = fminf(fmaxf(a2.x, -CL), CL);
    a2.y = fminf(fmaxf(a2.y, -CL), CL);
    a2.z = fminf(fmaxf(a2.z, -CL), CL);
    a2.w = fminf(fmaxf(a2.w, -CL), CL);

    float4* op = (float4*)out + (size_t)b * COUT * HW4 + (size_t)tile * 256 + tid;
    op[0 * HW4] = a0;
    op[1 * HW4] = a1;
    op[2 * HW4] = a2;
}

extern "C" void kernel_launch(void* const* d_in, const int* in_sizes, int n_in,
                              void* d_out, int out_size, void* d_ws, size_t ws_size,
                              hipStream_t stream) {
    const float* x        = (const float*)d_in[0];
    const float* w        = (const float*)d_in[1];
    const float* weight   = (const float*)d_in[2];
    const float* bias     = (const float*)d_in[3];
    const float* affine_w = (const float*)d_in[4];
    const float* affine_b = (const float*)d_in[5];
    float* out    = (float*)d_out;
    float* styles = (float*)d_ws;   // 8*256 floats = 8 KiB

    styles_kernel<<<dim3(B_), 256, 0, stream>>>(w, affine_w, affine_b, styles);
    modconv_kernel<<<dim3(HW / 1024, B_), 256, 0, stream>>>(x, styles, weight, bias, out);
}

// Round 3
// 92.753 us; speedup vs baseline: 1.3490x; 1.3490x over previous
//
#include <hip/hip_runtime.h>
#include <hip/hip_bf16.h>

// out[b,o,h,w] = clip( sum_c x[b,c,h,w] * w2d[o,c] * styles[b,c] + bias[o], -256, 256 )
// styles[b,c] = (dot(w[b,:], affine_w[c,:]) / sqrt(512) + affine_b[c]) / sqrt(256)
// B=8, C_in=256, H=W=256, C_out=3, w_dim=512.  All fp32.

#define B_    8
#define CIN   256
#define HW    65536          // 256*256
#define HW4   16384          // HW/4
#define COUT  3
#define WDIM  512

typedef float f4 __attribute__((ext_vector_type(4)));  // clang ext-vector: OK for nontemporal builtins

// One wave per (b,c): dot(w[b,:512], affine_w[c,:512]) via shfl reduce.
// Output: mod[b*256+c] = {w2d[0,c]*s, w2d[1,c]*s, w2d[2,c]*s, 0}
__global__ __launch_bounds__(256) void mod_kernel(
    const float* __restrict__ w,          // (B, 512)
    const float* __restrict__ affine_w,   // (256, 512)
    const float* __restrict__ affine_b,   // (256,)
    const float* __restrict__ weight,     // (3, 256)
    f4* __restrict__ mod)                 // (B*256,) out
{
    const int wid  = threadIdx.x >> 6;          // wave 0..3
    const int lane = threadIdx.x & 63;
    const int idx  = blockIdx.x * 4 + wid;      // 0..2047
    const int b    = idx >> 8;
    const int c    = idx & 255;

    const f4* aw = (const f4*)(affine_w + (size_t)c * WDIM) + lane * 2;
    const f4* wv = (const f4*)(w + (size_t)b * WDIM) + lane * 2;
    f4 a0 = aw[0], a1 = aw[1];
    f4 q0 = wv[0], q1 = wv[1];
    float acc = a0.x * q0.x + a0.y * q0.y + a0.z * q0.z + a0.w * q0.w
              + a1.x * q1.x + a1.y * q1.y + a1.z * q1.z + a1.w * q1.w;
#pragma unroll
    for (int off = 32; off >= 1; off >>= 1)
        acc += __shfl_xor(acc, off, 64);

    if (lane == 0) {
        const float rs512 = 0.044194173824159216f;  // 1/sqrt(512)
        const float rs256 = 0.0625f;                // 1/sqrt(256)
        float s = (acc * rs512 + affine_b[c]) * rs256;
        f4 m;
        m.x = weight[0 * CIN + c] * s;
        m.y = weight[1 * CIN + c] * s;
        m.z = weight[2 * CIN + c] * s;
        m.w = 0.f;
        mod[idx] = m;
    }
}

__global__ __launch_bounds__(256) void modconv_kernel(
    const float* __restrict__ x,        // (B, 256, 256, 256)
    const f4* __restrict__ mod,         // (B*256,) premodulated weights
    const float* __restrict__ bias,     // (3,)
    float* __restrict__ out)            // (B, 3, 256, 256)
{
    const int b    = blockIdx.y;
    const int tile = blockIdx.x;        // 64 tiles of 1024 floats each
    const int tid  = threadIdx.x;       // 256

    __shared__ f4 ms[CIN];
    ms[tid] = mod[b * CIN + tid];
    __syncthreads();

    const f4* xp = (const f4*)x + (size_t)b * CIN * HW4 + (size_t)tile * 256 + tid;

    const float b0 = bias[0], b1 = bias[1], b2 = bias[2];
    f4 a0 = {b0, b0, b0, b0};
    f4 a1 = {b1, b1, b1, b1};
    f4 a2 = {b2, b2, b2, b2};

#pragma unroll 16
    for (int c = 0; c < CIN; ++c) {
        f4 xv = __builtin_nontemporal_load(xp + (size_t)c * HW4);
        f4 m  = ms[c];
        a0.x = fmaf(xv.x, m.x, a0.x);
        a0.y = fmaf(xv.y, m.x, a0.y);
        a0.z = fmaf(xv.z, m.x, a0.z);
        a0.w = fmaf(xv.w, m.x, a0.w);
        a1.x = fmaf(xv.x, m.y, a1.x);
        a1.y = fmaf(xv.y, m.y, a1.y);
        a1.z = fmaf(xv.z, m.y, a1.z);
        a1.w = fmaf(xv.w, m.y, a1.w);
        a2.x = fmaf(xv.x, m.z, a2.x);
        a2.y = fmaf(xv.y, m.z, a2.y);
        a2.z = fmaf(xv.z, m.z, a2.z);
        a2.w = fmaf(xv.w, m.z, a2.w);
    }

    const float CL = 256.0f;
    a0.x = fminf(fmaxf(a0.x, -CL), CL);
    a0.y = fminf(fmaxf(a0.y, -CL), CL);
    a0.z = fminf(fmaxf(a0.z, -CL), CL);
    a0.w = fminf(fmaxf(a0.w, -CL), CL);
    a1.x = fminf(fmaxf(a1.x, -CL), CL);
    a1.y = fminf(fmaxf(a1.y, -CL), CL);
    a1.z = fminf(fmaxf(a1.z, -CL), CL);
    a1.w = fminf(fmaxf(a1.w, -CL), CL);
    a2.x = fminf(fmaxf(a2.x, -CL), CL);
    a2.y = fminf(fmaxf(a2.y, -CL), CL);
    a2.z = fminf(fmaxf(a2.z, -CL), CL);
    a2.w = fminf(fmaxf(a2.w, -CL), CL);

    f4* op = (f4*)out + (size_t)b * COUT * HW4 + (size_t)tile * 256 + tid;
    __builtin_nontemporal_store(a0, op + 0 * HW4);
    __builtin_nontemporal_store(a1, op + 1 * HW4);
    __builtin_nontemporal_store(a2, op + 2 * HW4);
}

extern "C" void kernel_launch(void* const* d_in, const int* in_sizes, int n_in,
                              void* d_out, int out_size, void* d_ws, size_t ws_size,
                              hipStream_t stream) {
    const float* x        = (const float*)d_in[0];
    const float* w        = (const float*)d_in[1];
    const float* weight   = (const float*)d_in[2];
    const float* bias     = (const float*)d_in[3];
    const float* affine_w = (const float*)d_in[4];
    const float* affine_b = (const float*)d_in[5];
    float* out = (float*)d_out;
    f4* mod    = (f4*)d_ws;   // 2048 f4 = 32 KiB

    mod_kernel<<<dim3(B_ * CIN / 4), 256, 0, stream>>>(w, affine_w, affine_b, weight, mod);
    modconv_kernel<<<dim3(HW / 1024, B_), 256, 0, stream>>>(x, mod, bias, out);
}